// Round 7
// baseline (267.651 us; speedup 1.0000x reference)
//
#include <hip/hip_runtime.h>
#include <hip/hip_bf16.h>
#include <cstdint>
#include <cstddef>

#define N_ROWS 8192
#define HDIM 512
#define INDIM 128
#define NHEADS 4
#define NNB 8

typedef __bf16 bf16_t;
typedef __bf16 bf16x8 __attribute__((ext_vector_type(8)));
typedef __bf16 bf16x4 __attribute__((ext_vector_type(4)));
typedef __bf16 bf16x2 __attribute__((ext_vector_type(2)));
typedef float f32x4 __attribute__((ext_vector_type(4)));

__device__ __forceinline__ float sigmoidf_(float x) { return 1.0f / (1.0f + expf(-x)); }

__device__ __forceinline__ void load_lds16(const void* g, void* l) {
  __builtin_amdgcn_global_load_lds(
      (const __attribute__((address_space(1))) void*)g,
      (__attribute__((address_space(3))) void*)l, 16, 0, 0);
}

// ---------------------------------------------------------------------------
// Pack: W1 = bf16([w_fg; w_ig]) (1024 x 2048),
//       W2i = bf16 gate-interleaved [w_ih | w_hh] (2048 x 640), row' = q*4+g,
//       b2[c'] = b_ih + b_hh (interleaved), A2[:, 0:128] = bf16(x)
// ---------------------------------------------------------------------------
__global__ __launch_bounds__(256) void pack_kernel(
    const float* __restrict__ w_fg, const float* __restrict__ w_ig,
    const float* __restrict__ w_ih, const float* __restrict__ w_hh,
    const float* __restrict__ b_ih, const float* __restrict__ b_hh,
    const float* __restrict__ x,
    bf16_t* __restrict__ W1, bf16_t* __restrict__ W2i,
    float* __restrict__ b2, bf16_t* __restrict__ A2)
{
  int idx = blockIdx.x * 256 + threadIdx.x;
  if (idx < 1024 * 2048) {
    int r = idx >> 11, k = idx & 2047;
    float v = (r < 512) ? w_fg[(size_t)r * 2048 + k] : w_ig[(size_t)(r - 512) * 2048 + k];
    W1[idx] = (bf16_t)v;
    return;
  }
  idx -= 1024 * 2048;
  if (idx < 2048 * 640) {
    int r = idx / 640, k = idx - r * 640;       // r = orig gate-major row g*512+q
    int rp = (r & 511) * 4 + (r >> 9);          // interleaved row q*4+g
    float v = (k < 128) ? w_ih[(size_t)r * 128 + k] : w_hh[(size_t)r * 512 + (k - 128)];
    W2i[(size_t)rp * 640 + k] = (bf16_t)v;
    return;
  }
  idx -= 2048 * 640;
  if (idx < 2048) {
    int q = idx >> 2, g = idx & 3;
    b2[idx] = b_ih[g * 512 + q] + b_hh[g * 512 + q];
    return;
  }
  idx -= 2048;
  if (idx < N_ROWS * INDIM) {
    int n = idx >> 7, cc = idx & 127;
    A2[(size_t)n * 640 + cc] = (bf16_t)x[idx];
  }
}

// ---------------------------------------------------------------------------
// Attention + aggregation: per-row softmax over 8 neighbors, agg -> bf16
// ---------------------------------------------------------------------------
__global__ __launch_bounds__(256) void attn_agg_kernel(
    const float* __restrict__ h, const float* __restrict__ hs,
    const float* __restrict__ a_src, bf16_t* __restrict__ agg)
{
  __shared__ float s_hs[NNB][HDIM];
  __shared__ float s_h[HDIM];
  __shared__ float s_logit[NNB][NHEADS];
  __shared__ float s_self[NHEADS];

  const int n = blockIdx.x;
  const int t = threadIdx.x;
  const float* hs_n = hs + (size_t)n * (NNB * HDIM);
  const float* h_n  = h  + (size_t)n * HDIM;

  {
    const float4* s4 = (const float4*)hs_n;
    float4* d4 = (float4*)&s_hs[0][0];
#pragma unroll
    for (int i = 0; i < 4; ++i) d4[t + i * 256] = s4[t + i * 256];
    if (t < HDIM / 4) ((float4*)s_h)[t] = ((const float4*)h_n)[t];
  }
  __syncthreads();

  const int wave = t >> 6, lane = t & 63;
#pragma unroll
  for (int kk = 0; kk < 2; ++kk) {
    const int k = wave * 2 + kk;
    float acc0 = 0.f, acc1 = 0.f, acc2 = 0.f, acc3 = 0.f;
#pragma unroll
    for (int i = 0; i < HDIM / 64; ++i) {
      const int hh = i * 64 + lane;
      const float v = s_hs[k][hh];
      const float4 av = *(const float4*)(a_src + (size_t)(HDIM + hh) * NHEADS);
      acc0 += v * av.x; acc1 += v * av.y; acc2 += v * av.z; acc3 += v * av.w;
    }
    float accs[NHEADS] = {acc0, acc1, acc2, acc3};
#pragma unroll
    for (int m = 0; m < NHEADS; ++m) {
      float a = accs[m];
#pragma unroll
      for (int off = 32; off > 0; off >>= 1) a += __shfl_xor(a, off);
      if (lane == 0) s_logit[k][m] = a;
    }
  }
  if (wave == 0) {
    float acc0 = 0.f, acc1 = 0.f, acc2 = 0.f, acc3 = 0.f;
#pragma unroll
    for (int i = 0; i < HDIM / 64; ++i) {
      const int hh = i * 64 + lane;
      const float v = s_h[hh];
      const float4 av = *(const float4*)(a_src + (size_t)hh * NHEADS);
      acc0 += v * av.x; acc1 += v * av.y; acc2 += v * av.z; acc3 += v * av.w;
    }
    float accs[NHEADS] = {acc0, acc1, acc2, acc3};
#pragma unroll
    for (int m = 0; m < NHEADS; ++m) {
      float a = accs[m];
#pragma unroll
      for (int off = 32; off > 0; off >>= 1) a += __shfl_xor(a, off);
      if (lane == 0) s_self[m] = a;
    }
  }
  __syncthreads();

  float w[NNB][NHEADS];
#pragma unroll
  for (int m = 0; m < NHEADS; ++m) {
    const float sm = s_self[m];
    float mx = -1e30f;
#pragma unroll
    for (int k = 0; k < NNB; ++k) {
      float l = sm + s_logit[k][m];
      l = (l >= 0.f) ? l : 0.2f * l;
      w[k][m] = l;
      mx = fmaxf(mx, l);
    }
    float sum = 0.f;
#pragma unroll
    for (int k = 0; k < NNB; ++k) { const float e = expf(w[k][m] - mx); w[k][m] = e; sum += e; }
    const float inv = 1.f / sum;
#pragma unroll
    for (int k = 0; k < NNB; ++k) w[k][m] *= inv;
  }

  bf16_t* agg_n = agg + (size_t)n * (NHEADS * HDIM);
  const int hh = t * 2;
  float e0[NNB], e1[NNB];
#pragma unroll
  for (int k = 0; k < NNB; ++k) { e0[k] = s_hs[k][hh]; e1[k] = s_hs[k][hh + 1]; }
#pragma unroll
  for (int m = 0; m < NHEADS; ++m) {
    float a0 = 0.f, a1 = 0.f;
#pragma unroll
    for (int k = 0; k < NNB; ++k) { a0 += w[k][m] * e0[k]; a1 += w[k][m] * e1[k]; }
    bf16x2 pk; pk[0] = (bf16_t)a0; pk[1] = (bf16_t)a1;
    *(bf16x2*)(agg_n + m * HDIM + hh) = pk;
  }
}

// ---------------------------------------------------------------------------
// 2-phase double-buffered bf16 GEMM, 128x128 tile, BK=64, 4 waves (64x64 each).
// Counted vmcnt(8) keeps next tile's loads in flight across the barrier (T4).
// DUAL-BK32 LDS BANKS: each K-tile stored as two [128][32] sub-buffers
// (64B row stride -> odd/even rows on different bank halves, 4-way max
// quad-alias; measured-good in round 1). global_load_lds fills each
// sub-buffer linearly (dest = base + tid*16); the layout split is carried
// entirely by the per-lane GLOBAL source address. No read-side swizzle.
// EPI 1: spatial-gate epilogue (cprime fp32, h' -> A2 bf16).
// EPI 2: gate-interleaved cols; fused LSTM finish via LDS -> writes out.
// ---------------------------------------------------------------------------
template <int EPI>
__global__ __launch_bounds__(256, 2) void gemm2p_kernel(
    const bf16_t* __restrict__ A, int lda,
    const bf16_t* __restrict__ Bt, int ldb, int K,
    const float* __restrict__ p0, const float* __restrict__ p1,
    const float* __restrict__ p2, const float* __restrict__ p3,
    float* __restrict__ q0, bf16_t* __restrict__ q1,
    float* __restrict__ out)
{
  __shared__ union {
    struct { bf16_t A[2][2][128][32]; bf16_t B[2][2][128][32]; } st;  // 64 KB
    float epi[128][128];                                              // 64 KB
  } sm;

  const int tid  = threadIdx.x;
  const int wave = tid >> 6, lane = tid & 63;
  const int wr = wave >> 1, wc = wave & 1;
  const int bm0 = blockIdx.x * 128;
  const int bn0 = blockIdx.y * 128;

  f32x4 acc[4][4] = {};

  // staging: per instruction (kk, r), thread tid covers
  //   row = r*64 + tid/4   (64 rows x 64B = 4KB block-wide),
  //   16B chunk = tid%4 within the 32-elem (64B) row of sub-buffer kk.
  // LDS dest byte = r*4096 + tid*16  (linear per wave, as required).
  const int srow = tid >> 2;            // 0..63
  const int sch8 = (tid & 3) * 8;       // bf16 offset of 16B chunk in 64B row

  const int frow = lane & 15;
  const int fq8  = (lane >> 4) * 8;     // 16B chunk of the 64B fragment row

  auto FB = [&]() {
    __builtin_amdgcn_sched_barrier(0);
    __builtin_amdgcn_s_barrier();
    __builtin_amdgcn_sched_barrier(0);
  };
  auto STAGE = [&](int buf, int k0) {
#pragma unroll
    for (int kk = 0; kk < 2; ++kk)
#pragma unroll
      for (int r = 0; r < 2; ++r)
        load_lds16(A + (size_t)(bm0 + r * 64 + srow) * lda + k0 + kk * 32 + sch8,
                   &sm.st.A[buf][kk][r * 64 + srow][sch8]);
#pragma unroll
    for (int kk = 0; kk < 2; ++kk)
#pragma unroll
      for (int r = 0; r < 2; ++r)
        load_lds16(Bt + (size_t)(bn0 + r * 64 + srow) * ldb + k0 + kk * 32 + sch8,
                   &sm.st.B[buf][kk][r * 64 + srow][sch8]);
  };
  auto COMPUTE = [&](int buf) {
#pragma unroll
    for (int kk = 0; kk < 2; ++kk) {
      bf16x8 af[4], bv[4];
#pragma unroll
      for (int i = 0; i < 4; ++i)
        af[i] = *(const bf16x8*)&sm.st.A[buf][kk][wr * 64 + i * 16 + frow][fq8];
#pragma unroll
      for (int j = 0; j < 4; ++j)
        bv[j] = *(const bf16x8*)&sm.st.B[buf][kk][wc * 64 + j * 16 + frow][fq8];
#pragma unroll
      for (int i = 0; i < 4; ++i)
#pragma unroll
        for (int j = 0; j < 4; ++j)
          acc[i][j] = __builtin_amdgcn_mfma_f32_16x16x32_bf16(af[i], bv[j], acc[i][j], 0, 0, 0);
    }
  };

  const int nt = K >> 6;  // BK = 64
  STAGE(0, 0);
  for (int t = 0; t < nt - 1; ++t) {
    STAGE((t + 1) & 1, (t + 1) * 64);
    asm volatile("s_waitcnt vmcnt(8)" ::: "memory");  // tile t landed; t+1 in flight
    FB();
    COMPUTE(t & 1);
    FB();
  }
  asm volatile("s_waitcnt vmcnt(0)" ::: "memory");
  FB();
  COMPUTE((nt - 1) & 1);

  const int col_in = lane & 15;
  const int row_in = (lane >> 4) * 4;

  if (EPI == 1) {
#pragma unroll
    for (int i = 0; i < 4; ++i) {
#pragma unroll
      for (int j = 0; j < 4; ++j) {
        const int col = bn0 + wc * 64 + j * 16 + col_in;
#pragma unroll
        for (int r = 0; r < 4; ++r) {
          const int row = bm0 + wr * 64 + i * 16 + row_in + r;
          const float v = acc[i][j][r];
          if (col < 512) {
            const float s = sigmoidf_(v + p0[col]);
            q0[(size_t)row * 512 + col] = p2[(size_t)row * 512 + col] * s;
          } else {
            const int jj = col - 512;
            const float s = sigmoidf_(v + p1[jj]);
            q1[(size_t)row * 640 + 128 + jj] = (bf16_t)(p3[(size_t)row * 512 + jj] * s);
          }
        }
      }
    }
  } else {
    // fused LSTM finish. cols are gate-interleaved: local col c = qi*4+g.
    FB();  // all K-loop LDS reads done in every wave before overwriting union
#pragma unroll
    for (int i = 0; i < 4; ++i)
#pragma unroll
      for (int j = 0; j < 4; ++j)
#pragma unroll
        for (int r = 0; r < 4; ++r)
          sm.epi[wr * 64 + i * 16 + row_in + r][wc * 64 + j * 16 + col_in] = acc[i][j][r];
    asm volatile("s_waitcnt lgkmcnt(0)" ::: "memory");  // ds_writes visible
    FB();
    const int q0i = bn0 >> 2;  // first global q of this block
#pragma unroll
    for (int pass = 0; pass < 16; ++pass) {
      const int idx = pass * 256 + tid;
      const int r  = idx >> 5;       // 0..127 local row
      const int qi = idx & 31;       // 0..31 local q
      const float4 g4 = *(const float4*)&sm.epi[r][qi * 4];
      const float4 bb = *(const float4*)&p0[(size_t)(q0i + qi) * 4];  // b2
      const int grow = bm0 + r;
      const int q    = q0i + qi;
      const float cp = p1[(size_t)grow * 512 + q];  // cprime
      const float ig = sigmoidf_(g4.x + bb.x);
      const float fg = sigmoidf_(g4.y + bb.y);
      const float gg = tanhf(g4.z + bb.z);
      const float og = sigmoidf_(g4.w + bb.w);
      const float cn = fg * cp + ig * gg;
      const float hn = og * tanhf(cn);
      out[(size_t)grow * 512 + q] = hn;
      out[(size_t)N_ROWS * 512 + (size_t)grow * 512 + q] = cn;
    }
  }
}

// ---------------------------------------------------------------------------
extern "C" void kernel_launch(void* const* d_in, const int* in_sizes, int n_in,
                              void* d_out, int out_size, void* d_ws, size_t ws_size,
                              hipStream_t stream) {
  const float* x     = (const float*)d_in[0];
  const float* h     = (const float*)d_in[1];
  const float* c     = (const float*)d_in[2];
  const float* hsp   = (const float*)d_in[3];
  const float* a_src = (const float*)d_in[4];
  const float* w_fg  = (const float*)d_in[5];
  const float* b_fg  = (const float*)d_in[6];
  const float* w_ig  = (const float*)d_in[7];
  const float* b_ig  = (const float*)d_in[8];
  const float* w_ih  = (const float*)d_in[9];
  const float* w_hh  = (const float*)d_in[10];
  const float* b_ih  = (const float*)d_in[11];
  const float* b_hh  = (const float*)d_in[12];
  float* out = (float*)d_out;

  uint8_t* ws = (uint8_t*)d_ws;
  bf16_t* agg    = (bf16_t*)(ws);                 // 8192*2048*2 = 33,554,432
  bf16_t* W1     = (bf16_t*)(ws + 33554432);      // 1024*2048*2 =  4,194,304
  bf16_t* W2i    = (bf16_t*)(ws + 37748736);      // 2048*640*2  =  2,621,440
  float*  b2     = (float*) (ws + 40370176);      // 2048*4      =      8,192
  bf16_t* A2     = (bf16_t*)(ws + 40378368);      // 8192*640*2  = 10,485,760
  float*  cprime = (float*) (ws + 50864128);      // 8192*512*4  = 16,777,216
  // total 67,641,344 bytes

  pack_kernel<<<17416, 256, 0, stream>>>(w_fg, w_ig, w_ih, w_hh, b_ih, b_hh, x,
                                         W1, W2i, b2, A2);
  attn_agg_kernel<<<N_ROWS, 256, 0, stream>>>(h, hsp, a_src, agg);
  gemm2p_kernel<1><<<dim3(64, 8), 256, 0, stream>>>(
      agg, 2048, W1, 2048, 2048, b_fg, b_ig, c, h, cprime, A2, nullptr);
  gemm2p_kernel<2><<<dim3(64, 16), 256, 0, stream>>>(
      A2, 640, W2i, 640, 640, b2, cprime, nullptr, nullptr, nullptr, nullptr, out);
}

// Round 8
// 228.224 us; speedup vs baseline: 1.1728x; 1.1728x over previous
//
#include <hip/hip_runtime.h>
#include <hip/hip_bf16.h>
#include <cstdint>
#include <cstddef>

#define N_ROWS 8192
#define HDIM 512
#define INDIM 128
#define NHEADS 4
#define NNB 8

typedef __bf16 bf16_t;
typedef __bf16 bf16x8 __attribute__((ext_vector_type(8)));
typedef __bf16 bf16x4 __attribute__((ext_vector_type(4)));
typedef __bf16 bf16x2 __attribute__((ext_vector_type(2)));
typedef float f32x4 __attribute__((ext_vector_type(4)));

__device__ __forceinline__ float sigmoidf_(float x) { return 1.0f / (1.0f + expf(-x)); }

__device__ __forceinline__ void load_lds16(const void* g, void* l) {
  __builtin_amdgcn_global_load_lds(
      (const __attribute__((address_space(1))) void*)g,
      (__attribute__((address_space(3))) void*)l, 16, 0, 0);
}

// ---------------------------------------------------------------------------
// Pack: W1 = bf16([w_fg; w_ig]) (1024 x 2048),
//       W2i = bf16 gate-interleaved [w_ih | w_hh] (2048 x 640), row' = q*4+g,
//       b2[c'] = b_ih + b_hh (interleaved), A2[:, 0:128] = bf16(x)
// ---------------------------------------------------------------------------
__global__ __launch_bounds__(256) void pack_kernel(
    const float* __restrict__ w_fg, const float* __restrict__ w_ig,
    const float* __restrict__ w_ih, const float* __restrict__ w_hh,
    const float* __restrict__ b_ih, const float* __restrict__ b_hh,
    const float* __restrict__ x,
    bf16_t* __restrict__ W1, bf16_t* __restrict__ W2i,
    float* __restrict__ b2, bf16_t* __restrict__ A2)
{
  int idx = blockIdx.x * 256 + threadIdx.x;
  if (idx < 1024 * 2048) {
    int r = idx >> 11, k = idx & 2047;
    float v = (r < 512) ? w_fg[(size_t)r * 2048 + k] : w_ig[(size_t)(r - 512) * 2048 + k];
    W1[idx] = (bf16_t)v;
    return;
  }
  idx -= 1024 * 2048;
  if (idx < 2048 * 640) {
    int r = idx / 640, k = idx - r * 640;       // r = orig gate-major row g*512+q
    int rp = (r & 511) * 4 + (r >> 9);          // interleaved row q*4+g
    float v = (k < 128) ? w_ih[(size_t)r * 128 + k] : w_hh[(size_t)r * 512 + (k - 128)];
    W2i[(size_t)rp * 640 + k] = (bf16_t)v;
    return;
  }
  idx -= 2048 * 640;
  if (idx < 2048) {
    int q = idx >> 2, g = idx & 3;
    b2[idx] = b_ih[g * 512 + q] + b_hh[g * 512 + q];
    return;
  }
  idx -= 2048;
  if (idx < N_ROWS * INDIM) {
    int n = idx >> 7, cc = idx & 127;
    A2[(size_t)n * 640 + cc] = (bf16_t)x[idx];
  }
}

// ---------------------------------------------------------------------------
// Attention + aggregation: per-row softmax over 8 neighbors, agg -> bf16
// ---------------------------------------------------------------------------
__global__ __launch_bounds__(256) void attn_agg_kernel(
    const float* __restrict__ h, const float* __restrict__ hs,
    const float* __restrict__ a_src, bf16_t* __restrict__ agg)
{
  __shared__ float s_hs[NNB][HDIM];
  __shared__ float s_h[HDIM];
  __shared__ float s_logit[NNB][NHEADS];
  __shared__ float s_self[NHEADS];

  const int n = blockIdx.x;
  const int t = threadIdx.x;
  const float* hs_n = hs + (size_t)n * (NNB * HDIM);
  const float* h_n  = h  + (size_t)n * HDIM;

  {
    const float4* s4 = (const float4*)hs_n;
    float4* d4 = (float4*)&s_hs[0][0];
#pragma unroll
    for (int i = 0; i < 4; ++i) d4[t + i * 256] = s4[t + i * 256];
    if (t < HDIM / 4) ((float4*)s_h)[t] = ((const float4*)h_n)[t];
  }
  __syncthreads();

  const int wave = t >> 6, lane = t & 63;
#pragma unroll
  for (int kk = 0; kk < 2; ++kk) {
    const int k = wave * 2 + kk;
    float acc0 = 0.f, acc1 = 0.f, acc2 = 0.f, acc3 = 0.f;
#pragma unroll
    for (int i = 0; i < HDIM / 64; ++i) {
      const int hh = i * 64 + lane;
      const float v = s_hs[k][hh];
      const float4 av = *(const float4*)(a_src + (size_t)(HDIM + hh) * NHEADS);
      acc0 += v * av.x; acc1 += v * av.y; acc2 += v * av.z; acc3 += v * av.w;
    }
    float accs[NHEADS] = {acc0, acc1, acc2, acc3};
#pragma unroll
    for (int m = 0; m < NHEADS; ++m) {
      float a = accs[m];
#pragma unroll
      for (int off = 32; off > 0; off >>= 1) a += __shfl_xor(a, off);
      if (lane == 0) s_logit[k][m] = a;
    }
  }
  if (wave == 0) {
    float acc0 = 0.f, acc1 = 0.f, acc2 = 0.f, acc3 = 0.f;
#pragma unroll
    for (int i = 0; i < HDIM / 64; ++i) {
      const int hh = i * 64 + lane;
      const float v = s_h[hh];
      const float4 av = *(const float4*)(a_src + (size_t)hh * NHEADS);
      acc0 += v * av.x; acc1 += v * av.y; acc2 += v * av.z; acc3 += v * av.w;
    }
    float accs[NHEADS] = {acc0, acc1, acc2, acc3};
#pragma unroll
    for (int m = 0; m < NHEADS; ++m) {
      float a = accs[m];
#pragma unroll
      for (int off = 32; off > 0; off >>= 1) a += __shfl_xor(a, off);
      if (lane == 0) s_self[m] = a;
    }
  }
  __syncthreads();

  float w[NNB][NHEADS];
#pragma unroll
  for (int m = 0; m < NHEADS; ++m) {
    const float sm = s_self[m];
    float mx = -1e30f;
#pragma unroll
    for (int k = 0; k < NNB; ++k) {
      float l = sm + s_logit[k][m];
      l = (l >= 0.f) ? l : 0.2f * l;
      w[k][m] = l;
      mx = fmaxf(mx, l);
    }
    float sum = 0.f;
#pragma unroll
    for (int k = 0; k < NNB; ++k) { const float e = expf(w[k][m] - mx); w[k][m] = e; sum += e; }
    const float inv = 1.f / sum;
#pragma unroll
    for (int k = 0; k < NNB; ++k) w[k][m] *= inv;
  }

  bf16_t* agg_n = agg + (size_t)n * (NHEADS * HDIM);
  const int hh = t * 2;
  float e0[NNB], e1[NNB];
#pragma unroll
  for (int k = 0; k < NNB; ++k) { e0[k] = s_hs[k][hh]; e1[k] = s_hs[k][hh + 1]; }
#pragma unroll
  for (int m = 0; m < NHEADS; ++m) {
    float a0 = 0.f, a1 = 0.f;
#pragma unroll
    for (int k = 0; k < NNB; ++k) { a0 += w[k][m] * e0[k]; a1 += w[k][m] * e1[k]; }
    bf16x2 pk; pk[0] = (bf16_t)a0; pk[1] = (bf16_t)a1;
    *(bf16x2*)(agg_n + m * HDIM + hh) = pk;
  }
}

// ---------------------------------------------------------------------------
// GEMM1 (spatial gates): round-1 structure (BK=32, single-buffer,
// __syncthreads, compiler-scheduled), tile 128x64 -> grid 64x16 = 1024
// blocks = 4 blocks/CU. 4 waves, each 64x32 (acc[4][2]).
// C = agg(8192x2048) @ W1^T(1024x2048): cols 0..511 forget, 512..1023 input.
// ---------------------------------------------------------------------------
__global__ __launch_bounds__(256) void gemm1_kernel(
    const bf16_t* __restrict__ A, const bf16_t* __restrict__ Bt,
    const float* __restrict__ b_fg, const float* __restrict__ b_ig,
    const float* __restrict__ c_in, const float* __restrict__ h_in,
    float* __restrict__ cprime, bf16_t* __restrict__ A2)
{
  __shared__ bf16_t At[128][32];   // 8 KB
  __shared__ bf16_t Bs[64][32];    // 4 KB

  const int tid  = threadIdx.x;
  const int wave = tid >> 6, lane = tid & 63;
  const int wr = wave >> 1, wc = wave & 1;
  const int bm0 = blockIdx.x * 128;
  const int bn0 = blockIdx.y * 64;
  const int K = 2048;

  f32x4 acc[4][2] = {};

  const int srow = tid >> 2;         // 0..63
  const int sch8 = (tid & 3) * 8;    // 16B chunk within 64B row
  const int frow = lane & 15;
  const int fq8  = (lane >> 4) * 8;

  for (int k0 = 0; k0 < K; k0 += 32) {
    load_lds16(A  + (size_t)(bm0 + srow)      * K + k0 + sch8, &At[srow][sch8]);
    load_lds16(A  + (size_t)(bm0 + 64 + srow) * K + k0 + sch8, &At[64 + srow][sch8]);
    load_lds16(Bt + (size_t)(bn0 + srow)      * K + k0 + sch8, &Bs[srow][sch8]);
    __syncthreads();

    bf16x8 af[4], bv[2];
#pragma unroll
    for (int i = 0; i < 4; ++i) af[i] = *(const bf16x8*)&At[wr * 64 + i * 16 + frow][fq8];
#pragma unroll
    for (int j = 0; j < 2; ++j) bv[j] = *(const bf16x8*)&Bs[wc * 32 + j * 16 + frow][fq8];
#pragma unroll
    for (int i = 0; i < 4; ++i)
#pragma unroll
      for (int j = 0; j < 2; ++j)
        acc[i][j] = __builtin_amdgcn_mfma_f32_16x16x32_bf16(af[i], bv[j], acc[i][j], 0, 0, 0);
    __syncthreads();
  }

  const int col_in = lane & 15;
  const int row_in = (lane >> 4) * 4;
#pragma unroll
  for (int i = 0; i < 4; ++i) {
#pragma unroll
    for (int j = 0; j < 2; ++j) {
      const int col = bn0 + wc * 32 + j * 16 + col_in;
#pragma unroll
      for (int r = 0; r < 4; ++r) {
        const int row = bm0 + wr * 64 + i * 16 + row_in + r;
        const float v = acc[i][j][r];
        if (col < 512) {
          const float s = sigmoidf_(v + b_fg[col]);
          cprime[(size_t)row * 512 + col] = c_in[(size_t)row * 512 + col] * s;
        } else {
          const int jj = col - 512;
          const float s = sigmoidf_(v + b_ig[jj]);
          A2[(size_t)row * 640 + 128 + jj] = (bf16_t)(h_in[(size_t)row * 512 + jj] * s);
        }
      }
    }
  }
}

// ---------------------------------------------------------------------------
// GEMM2 (LSTM gates, fused finish): round-1 structure, tile 128x128,
// grid 64x16 = 1024 blocks. Cols gate-interleaved (c = q*4+g). Fused LSTM
// epilogue via TWO-PASS fp32 LDS exchange (epi[64][128] = 32KB union),
// keeping fp32 precision and >=4 blocks/CU.
// ---------------------------------------------------------------------------
__global__ __launch_bounds__(256) void gemm2_kernel(
    const bf16_t* __restrict__ A, const bf16_t* __restrict__ Bt,
    const float* __restrict__ b2, const float* __restrict__ cprime,
    float* __restrict__ out)
{
  __shared__ union {
    struct { bf16_t A[128][32]; bf16_t B[128][32]; } st;  // 16 KB
    float epi[64][128];                                   // 32 KB
  } sm;

  const int tid  = threadIdx.x;
  const int wave = tid >> 6, lane = tid & 63;
  const int wr = wave >> 1, wc = wave & 1;
  const int bm0 = blockIdx.x * 128;
  const int bn0 = blockIdx.y * 128;
  const int K = 640;

  f32x4 acc[4][4] = {};

  const int srow = tid >> 2;
  const int sch8 = (tid & 3) * 8;
  const int frow = lane & 15;
  const int fq8  = (lane >> 4) * 8;

  for (int k0 = 0; k0 < K; k0 += 32) {
    load_lds16(A  + (size_t)(bm0 + srow)      * K + k0 + sch8, &sm.st.A[srow][sch8]);
    load_lds16(A  + (size_t)(bm0 + 64 + srow) * K + k0 + sch8, &sm.st.A[64 + srow][sch8]);
    load_lds16(Bt + (size_t)(bn0 + srow)      * K + k0 + sch8, &sm.st.B[srow][sch8]);
    load_lds16(Bt + (size_t)(bn0 + 64 + srow) * K + k0 + sch8, &sm.st.B[64 + srow][sch8]);
    __syncthreads();

    bf16x8 af[4], bv[4];
#pragma unroll
    for (int i = 0; i < 4; ++i) af[i] = *(const bf16x8*)&sm.st.A[wr * 64 + i * 16 + frow][fq8];
#pragma unroll
    for (int j = 0; j < 4; ++j) bv[j] = *(const bf16x8*)&sm.st.B[wc * 64 + j * 16 + frow][fq8];
#pragma unroll
    for (int i = 0; i < 4; ++i)
#pragma unroll
      for (int j = 0; j < 4; ++j)
        acc[i][j] = __builtin_amdgcn_mfma_f32_16x16x32_bf16(af[i], bv[j], acc[i][j], 0, 0, 0);
    __syncthreads();
  }

  // Fused LSTM finish: two passes over 64-row halves through fp32 LDS.
  const int col_in = lane & 15;
  const int row_in = (lane >> 4) * 4;
  const int q0i = bn0 >> 2;           // first global q of this block (32 q's)
  const int qi  = tid & 31;           // 0..31
  const int r0  = tid >> 5;           // 0..7

#pragma unroll
  for (int p = 0; p < 2; ++p) {
    if (wr == p) {
#pragma unroll
      for (int i = 0; i < 4; ++i)
#pragma unroll
        for (int j = 0; j < 4; ++j)
#pragma unroll
          for (int r = 0; r < 4; ++r)
            sm.epi[i * 16 + row_in + r][wc * 64 + j * 16 + col_in] = acc[i][j][r];
    }
    __syncthreads();
    const float4 bb = *(const float4*)&b2[(size_t)(q0i + qi) * 4];
#pragma unroll
    for (int rr = 0; rr < 8; ++rr) {
      const int lr = r0 + rr * 8;               // 0..63 local row in this half
      const float4 g4 = *(const float4*)&sm.epi[lr][qi * 4];
      const int grow = bm0 + p * 64 + lr;
      const int q    = q0i + qi;
      const float cp = cprime[(size_t)grow * 512 + q];
      const float ig = sigmoidf_(g4.x + bb.x);
      const float fg = sigmoidf_(g4.y + bb.y);
      const float gg = tanhf(g4.z + bb.z);
      const float og = sigmoidf_(g4.w + bb.w);
      const float cn = fg * cp + ig * gg;
      const float hn = og * tanhf(cn);
      out[(size_t)grow * 512 + q] = hn;
      out[(size_t)N_ROWS * 512 + (size_t)grow * 512 + q] = cn;
    }
    __syncthreads();
  }
}

// ---------------------------------------------------------------------------
extern "C" void kernel_launch(void* const* d_in, const int* in_sizes, int n_in,
                              void* d_out, int out_size, void* d_ws, size_t ws_size,
                              hipStream_t stream) {
  const float* x     = (const float*)d_in[0];
  const float* h     = (const float*)d_in[1];
  const float* c     = (const float*)d_in[2];
  const float* hsp   = (const float*)d_in[3];
  const float* a_src = (const float*)d_in[4];
  const float* w_fg  = (const float*)d_in[5];
  const float* b_fg  = (const float*)d_in[6];
  const float* w_ig  = (const float*)d_in[7];
  const float* b_ig  = (const float*)d_in[8];
  const float* w_ih  = (const float*)d_in[9];
  const float* w_hh  = (const float*)d_in[10];
  const float* b_ih  = (const float*)d_in[11];
  const float* b_hh  = (const float*)d_in[12];
  float* out = (float*)d_out;

  uint8_t* ws = (uint8_t*)d_ws;
  bf16_t* agg    = (bf16_t*)(ws);                 // 8192*2048*2 = 33,554,432
  bf16_t* W1     = (bf16_t*)(ws + 33554432);      // 1024*2048*2 =  4,194,304
  bf16_t* W2i    = (bf16_t*)(ws + 37748736);      // 2048*640*2  =  2,621,440
  float*  b2     = (float*) (ws + 40370176);      // 2048*4      =      8,192
  bf16_t* A2     = (bf16_t*)(ws + 40378368);      // 8192*640*2  = 10,485,760
  float*  cprime = (float*) (ws + 50864128);      // 8192*512*4  = 16,777,216
  // total 67,641,344 bytes

  pack_kernel<<<17416, 256, 0, stream>>>(w_fg, w_ig, w_ih, w_hh, b_ih, b_hh, x,
                                         W1, W2i, b2, A2);
  attn_agg_kernel<<<N_ROWS, 256, 0, stream>>>(h, hsp, a_src, agg);
  gemm1_kernel<<<dim3(64, 16), 256, 0, stream>>>(
      agg, W1, b_fg, b_ig, c, h, cprime, A2);
  gemm2_kernel<<<dim3(64, 16), 256, 0, stream>>>(
      A2, W2i, b2, cprime, out);
}

// Round 10
// 193.359 us; speedup vs baseline: 1.3842x; 1.1803x over previous
//
#include <hip/hip_runtime.h>
#include <hip/hip_bf16.h>
#include <cstdint>
#include <cstddef>

#define N_ROWS 8192
#define HDIM 512
#define INDIM 128
#define NHEADS 4
#define NNB 8

typedef __bf16 bf16_t;
typedef __bf16 bf16x8 __attribute__((ext_vector_type(8)));
typedef __bf16 bf16x4 __attribute__((ext_vector_type(4)));
typedef __bf16 bf16x2 __attribute__((ext_vector_type(2)));
typedef float f32x4 __attribute__((ext_vector_type(4)));

__device__ __forceinline__ float sigmoidf_(float x) { return 1.0f / (1.0f + expf(-x)); }

__device__ __forceinline__ void load_lds16(const void* g, void* l) {
  __builtin_amdgcn_global_load_lds(
      (const __attribute__((address_space(1))) void*)g,
      (__attribute__((address_space(3))) void*)l, 16, 0, 0);
}

// ---------------------------------------------------------------------------
// Pack: W1 = bf16([w_fg; w_ig]) (1024 x 2048),
//       W2i = bf16 gate-interleaved [w_ih | w_hh] (2048 x 640), row' = q*4+g,
//       b2[c'] = b_ih + b_hh (interleaved), A2[:, 0:128] = bf16(x)
// ---------------------------------------------------------------------------
__global__ __launch_bounds__(256) void pack_kernel(
    const float* __restrict__ w_fg, const float* __restrict__ w_ig,
    const float* __restrict__ w_ih, const float* __restrict__ w_hh,
    const float* __restrict__ b_ih, const float* __restrict__ b_hh,
    const float* __restrict__ x,
    bf16_t* __restrict__ W1, bf16_t* __restrict__ W2i,
    float* __restrict__ b2, bf16_t* __restrict__ A2)
{
  int idx = blockIdx.x * 256 + threadIdx.x;
  if (idx < 1024 * 2048) {
    int r = idx >> 11, k = idx & 2047;
    float v = (r < 512) ? w_fg[(size_t)r * 2048 + k] : w_ig[(size_t)(r - 512) * 2048 + k];
    W1[idx] = (bf16_t)v;
    return;
  }
  idx -= 1024 * 2048;
  if (idx < 2048 * 640) {
    int r = idx / 640, k = idx - r * 640;       // r = orig gate-major row g*512+q
    int rp = (r & 511) * 4 + (r >> 9);          // interleaved row q*4+g
    float v = (k < 128) ? w_ih[(size_t)r * 128 + k] : w_hh[(size_t)r * 512 + (k - 128)];
    W2i[(size_t)rp * 640 + k] = (bf16_t)v;
    return;
  }
  idx -= 2048 * 640;
  if (idx < 2048) {
    int q = idx >> 2, g = idx & 3;
    b2[idx] = b_ih[g * 512 + q] + b_hh[g * 512 + q];
    return;
  }
  idx -= 2048;
  if (idx < N_ROWS * INDIM) {
    int n = idx >> 7, cc = idx & 127;
    A2[(size_t)n * 640 + cc] = (bf16_t)x[idx];
  }
}

// ---------------------------------------------------------------------------
// Attention + aggregation: per-row softmax over 8 neighbors, agg -> bf16
// ---------------------------------------------------------------------------
__global__ __launch_bounds__(256) void attn_agg_kernel(
    const float* __restrict__ h, const float* __restrict__ hs,
    const float* __restrict__ a_src, bf16_t* __restrict__ agg)
{
  __shared__ float s_hs[NNB][HDIM];
  __shared__ float s_h[HDIM];
  __shared__ float s_logit[NNB][NHEADS];
  __shared__ float s_self[NHEADS];

  const int n = blockIdx.x;
  const int t = threadIdx.x;
  const float* hs_n = hs + (size_t)n * (NNB * HDIM);
  const float* h_n  = h  + (size_t)n * HDIM;

  {
    const float4* s4 = (const float4*)hs_n;
    float4* d4 = (float4*)&s_hs[0][0];
#pragma unroll
    for (int i = 0; i < 4; ++i) d4[t + i * 256] = s4[t + i * 256];
    if (t < HDIM / 4) ((float4*)s_h)[t] = ((const float4*)h_n)[t];
  }
  __syncthreads();

  const int wave = t >> 6, lane = t & 63;
#pragma unroll
  for (int kk = 0; kk < 2; ++kk) {
    const int k = wave * 2 + kk;
    float acc0 = 0.f, acc1 = 0.f, acc2 = 0.f, acc3 = 0.f;
#pragma unroll
    for (int i = 0; i < HDIM / 64; ++i) {
      const int hh = i * 64 + lane;
      const float v = s_hs[k][hh];
      const float4 av = *(const float4*)(a_src + (size_t)(HDIM + hh) * NHEADS);
      acc0 += v * av.x; acc1 += v * av.y; acc2 += v * av.z; acc3 += v * av.w;
    }
    float accs[NHEADS] = {acc0, acc1, acc2, acc3};
#pragma unroll
    for (int m = 0; m < NHEADS; ++m) {
      float a = accs[m];
#pragma unroll
      for (int off = 32; off > 0; off >>= 1) a += __shfl_xor(a, off);
      if (lane == 0) s_logit[k][m] = a;
    }
  }
  if (wave == 0) {
    float acc0 = 0.f, acc1 = 0.f, acc2 = 0.f, acc3 = 0.f;
#pragma unroll
    for (int i = 0; i < HDIM / 64; ++i) {
      const int hh = i * 64 + lane;
      const float v = s_h[hh];
      const float4 av = *(const float4*)(a_src + (size_t)hh * NHEADS);
      acc0 += v * av.x; acc1 += v * av.y; acc2 += v * av.z; acc3 += v * av.w;
    }
    float accs[NHEADS] = {acc0, acc1, acc2, acc3};
#pragma unroll
    for (int m = 0; m < NHEADS; ++m) {
      float a = accs[m];
#pragma unroll
      for (int off = 32; off > 0; off >>= 1) a += __shfl_xor(a, off);
      if (lane == 0) s_self[m] = a;
    }
  }
  __syncthreads();

  float w[NNB][NHEADS];
#pragma unroll
  for (int m = 0; m < NHEADS; ++m) {
    const float sm = s_self[m];
    float mx = -1e30f;
#pragma unroll
    for (int k = 0; k < NNB; ++k) {
      float l = sm + s_logit[k][m];
      l = (l >= 0.f) ? l : 0.2f * l;
      w[k][m] = l;
      mx = fmaxf(mx, l);
    }
    float sum = 0.f;
#pragma unroll
    for (int k = 0; k < NNB; ++k) { const float e = expf(w[k][m] - mx); w[k][m] = e; sum += e; }
    const float inv = 1.f / sum;
#pragma unroll
    for (int k = 0; k < NNB; ++k) w[k][m] *= inv;
  }

  bf16_t* agg_n = agg + (size_t)n * (NHEADS * HDIM);
  const int hh = t * 2;
  float e0[NNB], e1[NNB];
#pragma unroll
  for (int k = 0; k < NNB; ++k) { e0[k] = s_hs[k][hh]; e1[k] = s_hs[k][hh + 1]; }
#pragma unroll
  for (int m = 0; m < NHEADS; ++m) {
    float a0 = 0.f, a1 = 0.f;
#pragma unroll
    for (int k = 0; k < NNB; ++k) { a0 += w[k][m] * e0[k]; a1 += w[k][m] * e1[k]; }
    bf16x2 pk; pk[0] = (bf16_t)a0; pk[1] = (bf16_t)a1;
    *(bf16x2*)(agg_n + m * HDIM + hh) = pk;
  }
}

// ---------------------------------------------------------------------------
// GEMM1 (spatial gates): BK=32, single-buffer, compiler-scheduled, tile
// 128x64, grid 64x16 = 1024 blocks. CHUNK-XOR SWIZZLE on [R][32] tiles:
// logical 16B chunk q of row r lives at physical chunk q ^ ((r>>1)&3).
// Applied rule-#21 style: pre-swizzled GLOBAL source + linear LDS dest
// (global_load_lds) + same XOR on the read side. Each 16-lane quarter of a
// ds_read_b128 then covers all 8 granule-positions exactly 2x -> conflict-free.
// ---------------------------------------------------------------------------
__global__ __launch_bounds__(256) void gemm1_kernel(
    const bf16_t* __restrict__ A, const bf16_t* __restrict__ Bt,
    const float* __restrict__ b_fg, const float* __restrict__ b_ig,
    const float* __restrict__ c_in, const float* __restrict__ h_in,
    float* __restrict__ cprime, bf16_t* __restrict__ A2)
{
  __shared__ bf16_t At[128][32];   // 8 KB
  __shared__ bf16_t Bs[64][32];    // 4 KB

  const int tid  = threadIdx.x;
  const int wave = tid >> 6, lane = tid & 63;
  const int wr = wave >> 1, wc = wave & 1;
  const int bm0 = blockIdx.x * 128;
  const int bn0 = blockIdx.y * 64;
  const int K = 2048;

  f32x4 acc[4][2] = {};

  const int srow = tid >> 2;                         // 0..63
  const int sch  = tid & 3;                          // physical 16B chunk
  const int gsw8 = (sch ^ ((srow >> 1) & 3)) * 8;    // pre-swizzled global chunk
  const int sch8 = sch * 8;                          // linear LDS dest
  const int frow = lane & 15;
  const int fro8 = ((lane >> 4) ^ ((frow >> 1) & 3)) * 8;  // swizzled read chunk

  for (int k0 = 0; k0 < K; k0 += 32) {
    load_lds16(A  + (size_t)(bm0 + srow)      * K + k0 + gsw8, &At[srow][sch8]);
    load_lds16(A  + (size_t)(bm0 + 64 + srow) * K + k0 + gsw8, &At[64 + srow][sch8]);
    load_lds16(Bt + (size_t)(bn0 + srow)      * K + k0 + gsw8, &Bs[srow][sch8]);
    __syncthreads();

    bf16x8 af[4], bv[2];
#pragma unroll
    for (int i = 0; i < 4; ++i) af[i] = *(const bf16x8*)&At[wr * 64 + i * 16 + frow][fro8];
#pragma unroll
    for (int j = 0; j < 2; ++j) bv[j] = *(const bf16x8*)&Bs[wc * 32 + j * 16 + frow][fro8];
#pragma unroll
    for (int i = 0; i < 4; ++i)
#pragma unroll
      for (int j = 0; j < 2; ++j)
        acc[i][j] = __builtin_amdgcn_mfma_f32_16x16x32_bf16(af[i], bv[j], acc[i][j], 0, 0, 0);
    __syncthreads();
  }

  const int col_in = lane & 15;
  const int row_in = (lane >> 4) * 4;
#pragma unroll
  for (int i = 0; i < 4; ++i) {
#pragma unroll
    for (int j = 0; j < 2; ++j) {
      const int col = bn0 + wc * 32 + j * 16 + col_in;
#pragma unroll
      for (int r = 0; r < 4; ++r) {
        const int row = bm0 + wr * 64 + i * 16 + row_in + r;
        const float v = acc[i][j][r];
        if (col < 512) {
          const float s = sigmoidf_(v + b_fg[col]);
          cprime[(size_t)row * 512 + col] = c_in[(size_t)row * 512 + col] * s;
        } else {
          const int jj = col - 512;
          const float s = sigmoidf_(v + b_ig[jj]);
          A2[(size_t)row * 640 + 128 + jj] = (bf16_t)(h_in[(size_t)row * 512 + jj] * s);
        }
      }
    }
  }
}

// ---------------------------------------------------------------------------
// GEMM2 (LSTM gates, fused finish): BK=32, tile 128x128, grid 64x16.
// Same chunk-XOR swizzle as gemm1. Cols gate-interleaved (c = q*4+g).
// Fused LSTM epilogue via two-pass fp32 LDS exchange (epi[64][128] union).
// ---------------------------------------------------------------------------
__global__ __launch_bounds__(256) void gemm2_kernel(
    const bf16_t* __restrict__ A, const bf16_t* __restrict__ Bt,
    const float* __restrict__ b2, const float* __restrict__ cprime,
    float* __restrict__ out)
{
  __shared__ union {
    struct { bf16_t A[128][32]; bf16_t B[128][32]; } st;  // 16 KB
    float epi[64][128];                                   // 32 KB
  } sm;

  const int tid  = threadIdx.x;
  const int wave = tid >> 6, lane = tid & 63;
  const int wr = wave >> 1, wc = wave & 1;
  const int bm0 = blockIdx.x * 128;
  const int bn0 = blockIdx.y * 128;
  const int K = 640;

  f32x4 acc[4][4] = {};

  const int srow = tid >> 2;
  const int sch  = tid & 3;
  const int gsw8 = (sch ^ ((srow >> 1) & 3)) * 8;
  const int sch8 = sch * 8;
  const int frow = lane & 15;
  const int fro8 = ((lane >> 4) ^ ((frow >> 1) & 3)) * 8;

  for (int k0 = 0; k0 < K; k0 += 32) {
    load_lds16(A  + (size_t)(bm0 + srow)      * K + k0 + gsw8, &sm.st.A[srow][sch8]);
    load_lds16(A  + (size_t)(bm0 + 64 + srow) * K + k0 + gsw8, &sm.st.A[64 + srow][sch8]);
    load_lds16(Bt + (size_t)(bn0 + srow)      * K + k0 + gsw8, &sm.st.B[srow][sch8]);
    load_lds16(Bt + (size_t)(bn0 + 64 + srow) * K + k0 + gsw8, &sm.st.B[64 + srow][sch8]);
    __syncthreads();

    bf16x8 af[4], bv[4];
#pragma unroll
    for (int i = 0; i < 4; ++i) af[i] = *(const bf16x8*)&sm.st.A[wr * 64 + i * 16 + frow][fro8];
#pragma unroll
    for (int j = 0; j < 4; ++j) bv[j] = *(const bf16x8*)&sm.st.B[wc * 64 + j * 16 + frow][fro8];
#pragma unroll
    for (int i = 0; i < 4; ++i)
#pragma unroll
      for (int j = 0; j < 4; ++j)
        acc[i][j] = __builtin_amdgcn_mfma_f32_16x16x32_bf16(af[i], bv[j], acc[i][j], 0, 0, 0);
    __syncthreads();
  }

  // Fused LSTM finish: two passes over 64-row halves through fp32 LDS.
  const int col_in = lane & 15;
  const int row_in = (lane >> 4) * 4;
  const int q0i = bn0 >> 2;           // first global q of this block (32 q's)
  const int qi  = tid & 31;           // 0..31
  const int r0  = tid >> 5;           // 0..7

#pragma unroll
  for (int p = 0; p < 2; ++p) {
    if (wr == p) {
#pragma unroll
      for (int i = 0; i < 4; ++i)
#pragma unroll
        for (int j = 0; j < 4; ++j)
#pragma unroll
          for (int r = 0; r < 4; ++r)
            sm.epi[i * 16 + row_in + r][wc * 64 + j * 16 + col_in] = acc[i][j][r];
    }
    __syncthreads();
    const float4 bb = *(const float4*)&b2[(size_t)(q0i + qi) * 4];
#pragma unroll
    for (int rr = 0; rr < 8; ++rr) {
      const int lr = r0 + rr * 8;               // 0..63 local row in this half
      const float4 g4 = *(const float4*)&sm.epi[lr][qi * 4];
      const int grow = bm0 + p * 64 + lr;
      const int q    = q0i + qi;
      const float cp = cprime[(size_t)grow * 512 + q];
      const float ig = sigmoidf_(g4.x + bb.x);
      const float fg = sigmoidf_(g4.y + bb.y);
      const float gg = tanhf(g4.z + bb.z);
      const float og = sigmoidf_(g4.w + bb.w);
      const float cn = fg * cp + ig * gg;
      const float hn = og * tanhf(cn);
      out[(size_t)grow * 512 + q] = hn;
      out[(size_t)N_ROWS * 512 + (size_t)grow * 512 + q] = cn;
    }
    __syncthreads();
  }
}

// ---------------------------------------------------------------------------
extern "C" void kernel_launch(void* const* d_in, const int* in_sizes, int n_in,
                              void* d_out, int out_size, void* d_ws, size_t ws_size,
                              hipStream_t stream) {
  const float* x     = (const float*)d_in[0];
  const float* h     = (const float*)d_in[1];
  const float* c     = (const float*)d_in[2];
  const float* hsp   = (const float*)d_in[3];
  const float* a_src = (const float*)d_in[4];
  const float* w_fg  = (const float*)d_in[5];
  const float* b_fg  = (const float*)d_in[6];
  const float* w_ig  = (const float*)d_in[7];
  const float* b_ig  = (const float*)d_in[8];
  const float* w_ih  = (const float*)d_in[9];
  const float* w_hh  = (const float*)d_in[10];
  const float* b_ih  = (const float*)d_in[11];
  const float* b_hh  = (const float*)d_in[12];
  float* out = (float*)d_out;

  uint8_t* ws = (uint8_t*)d_ws;
  bf16_t* agg    = (bf16_t*)(ws);                 // 8192*2048*2 = 33,554,432
  bf16_t* W1     = (bf16_t*)(ws + 33554432);      // 1024*2048*2 =  4,194,304
  bf16_t* W2i    = (bf16_t*)(ws + 37748736);      // 2048*640*2  =  2,621,440
  float*  b2     = (float*) (ws + 40370176);      // 2048*4      =      8,192
  bf16_t* A2     = (bf16_t*)(ws + 40378368);      // 8192*640*2  = 10,485,760
  float*  cprime = (float*) (ws + 50864128);      // 8192*512*4  = 16,777,216
  // total 67,641,344 bytes

  pack_kernel<<<17416, 256, 0, stream>>>(w_fg, w_ig, w_ih, w_hh, b_ih, b_hh, x,
                                         W1, W2i, b2, A2);
  attn_agg_kernel<<<N_ROWS, 256, 0, stream>>>(h, hsp, a_src, agg);
  gemm1_kernel<<<dim3(64, 16), 256, 0, stream>>>(
      agg, W1, b_fg, b_ig, c, h, cprime, A2);
  gemm2_kernel<<<dim3(64, 16), 256, 0, stream>>>(
      A2, W2i, b2, cprime, out);
}

// Round 11
// 186.201 us; speedup vs baseline: 1.4374x; 1.0384x over previous
//
#include <hip/hip_runtime.h>
#include <hip/hip_bf16.h>
#include <cstdint>
#include <cstddef>

#define N_ROWS 8192
#define HDIM 512
#define INDIM 128
#define NHEADS 4
#define NNB 8

typedef __bf16 bf16_t;
typedef __bf16 bf16x8 __attribute__((ext_vector_type(8)));
typedef __bf16 bf16x4 __attribute__((ext_vector_type(4)));
typedef __bf16 bf16x2 __attribute__((ext_vector_type(2)));
typedef float f32x4 __attribute__((ext_vector_type(4)));

__device__ __forceinline__ float sigmoidf_(float x) { return 1.0f / (1.0f + expf(-x)); }

__device__ __forceinline__ void load_lds16(const void* g, void* l) {
  __builtin_amdgcn_global_load_lds(
      (const __attribute__((address_space(1))) void*)g,
      (__attribute__((address_space(3))) void*)l, 16, 0, 0);
}

// ---------------------------------------------------------------------------
// Pack (vectorized 4-wide): W1 = bf16([w_fg; w_ig]) (1024 x 2048),
//   W2i = bf16 gate-interleaved [w_ih | w_hh] (2048 x 640), row' = q*4+g,
//   b2[c'] = b_ih + b_hh (interleaved), A2[:, 0:128] = bf16(x)
// ---------------------------------------------------------------------------
__global__ __launch_bounds__(256) void pack_kernel(
    const float* __restrict__ w_fg, const float* __restrict__ w_ig,
    const float* __restrict__ w_ih, const float* __restrict__ w_hh,
    const float* __restrict__ b_ih, const float* __restrict__ b_hh,
    const float* __restrict__ x,
    bf16_t* __restrict__ W1, bf16_t* __restrict__ W2i,
    float* __restrict__ b2, bf16_t* __restrict__ A2)
{
  int idx = blockIdx.x * 256 + threadIdx.x;
  if (idx < 524288) {                       // W1: 4 elems/thread
    const int e = idx * 4, r = e >> 11, k = e & 2047;
    const float* src = (r < 512) ? &w_fg[(size_t)r * 2048 + k]
                                 : &w_ig[(size_t)(r - 512) * 2048 + k];
    const float4 v = *(const float4*)src;
    bf16x4 o; o[0] = (bf16_t)v.x; o[1] = (bf16_t)v.y; o[2] = (bf16_t)v.z; o[3] = (bf16_t)v.w;
    *(bf16x4*)&W1[e] = o;
    return;
  }
  idx -= 524288;
  if (idx < 327680) {                       // W2i: 4 elems/thread
    const int e = idx * 4, r = e / 640, k = e - r * 640;   // k multiple of 4
    const int rp = (r & 511) * 4 + (r >> 9);
    const float* src = (k < 128) ? &w_ih[(size_t)r * 128 + k]
                                 : &w_hh[(size_t)r * 512 + (k - 128)];
    const float4 v = *(const float4*)src;
    bf16x4 o; o[0] = (bf16_t)v.x; o[1] = (bf16_t)v.y; o[2] = (bf16_t)v.z; o[3] = (bf16_t)v.w;
    *(bf16x4*)&W2i[(size_t)rp * 640 + k] = o;
    return;
  }
  idx -= 327680;
  if (idx < 2048) {                         // b2
    const int q = idx >> 2, g = idx & 3;
    b2[idx] = b_ih[g * 512 + q] + b_hh[g * 512 + q];
    return;
  }
  idx -= 2048;
  if (idx < 262144) {                       // x -> A2[:, :128]
    const int e = idx * 4, n = e >> 7, cc = e & 127;
    const float4 v = *(const float4*)&x[e];
    bf16x4 o; o[0] = (bf16_t)v.x; o[1] = (bf16_t)v.y; o[2] = (bf16_t)v.z; o[3] = (bf16_t)v.w;
    *(bf16x4*)&A2[(size_t)n * 640 + cc] = o;
  }
}

// ---------------------------------------------------------------------------
// Attention + aggregation: per-row softmax over 8 neighbors, agg -> bf16
// ---------------------------------------------------------------------------
__global__ __launch_bounds__(256) void attn_agg_kernel(
    const float* __restrict__ h, const float* __restrict__ hs,
    const float* __restrict__ a_src, bf16_t* __restrict__ agg)
{
  __shared__ float s_hs[NNB][HDIM];
  __shared__ float s_h[HDIM];
  __shared__ float s_logit[NNB][NHEADS];
  __shared__ float s_self[NHEADS];

  const int n = blockIdx.x;
  const int t = threadIdx.x;
  const float* hs_n = hs + (size_t)n * (NNB * HDIM);
  const float* h_n  = h  + (size_t)n * HDIM;

  {
    const float4* s4 = (const float4*)hs_n;
    float4* d4 = (float4*)&s_hs[0][0];
#pragma unroll
    for (int i = 0; i < 4; ++i) d4[t + i * 256] = s4[t + i * 256];
    if (t < HDIM / 4) ((float4*)s_h)[t] = ((const float4*)h_n)[t];
  }
  __syncthreads();

  const int wave = t >> 6, lane = t & 63;
#pragma unroll
  for (int kk = 0; kk < 2; ++kk) {
    const int k = wave * 2 + kk;
    float acc0 = 0.f, acc1 = 0.f, acc2 = 0.f, acc3 = 0.f;
#pragma unroll
    for (int i = 0; i < HDIM / 64; ++i) {
      const int hh = i * 64 + lane;
      const float v = s_hs[k][hh];
      const float4 av = *(const float4*)(a_src + (size_t)(HDIM + hh) * NHEADS);
      acc0 += v * av.x; acc1 += v * av.y; acc2 += v * av.z; acc3 += v * av.w;
    }
    float accs[NHEADS] = {acc0, acc1, acc2, acc3};
#pragma unroll
    for (int m = 0; m < NHEADS; ++m) {
      float a = accs[m];
#pragma unroll
      for (int off = 32; off > 0; off >>= 1) a += __shfl_xor(a, off);
      if (lane == 0) s_logit[k][m] = a;
    }
  }
  if (wave == 0) {
    float acc0 = 0.f, acc1 = 0.f, acc2 = 0.f, acc3 = 0.f;
#pragma unroll
    for (int i = 0; i < HDIM / 64; ++i) {
      const int hh = i * 64 + lane;
      const float v = s_h[hh];
      const float4 av = *(const float4*)(a_src + (size_t)hh * NHEADS);
      acc0 += v * av.x; acc1 += v * av.y; acc2 += v * av.z; acc3 += v * av.w;
    }
    float accs[NHEADS] = {acc0, acc1, acc2, acc3};
#pragma unroll
    for (int m = 0; m < NHEADS; ++m) {
      float a = accs[m];
#pragma unroll
      for (int off = 32; off > 0; off >>= 1) a += __shfl_xor(a, off);
      if (lane == 0) s_self[m] = a;
    }
  }
  __syncthreads();

  float w[NNB][NHEADS];
#pragma unroll
  for (int m = 0; m < NHEADS; ++m) {
    const float sm = s_self[m];
    float mx = -1e30f;
#pragma unroll
    for (int k = 0; k < NNB; ++k) {
      float l = sm + s_logit[k][m];
      l = (l >= 0.f) ? l : 0.2f * l;
      w[k][m] = l;
      mx = fmaxf(mx, l);
    }
    float sum = 0.f;
#pragma unroll
    for (int k = 0; k < NNB; ++k) { const float e = expf(w[k][m] - mx); w[k][m] = e; sum += e; }
    const float inv = 1.f / sum;
#pragma unroll
    for (int k = 0; k < NNB; ++k) w[k][m] *= inv;
  }

  bf16_t* agg_n = agg + (size_t)n * (NHEADS * HDIM);
  const int hh = t * 2;
  float e0[NNB], e1[NNB];
#pragma unroll
  for (int k = 0; k < NNB; ++k) { e0[k] = s_hs[k][hh]; e1[k] = s_hs[k][hh + 1]; }
#pragma unroll
  for (int m = 0; m < NHEADS; ++m) {
    float a0 = 0.f, a1 = 0.f;
#pragma unroll
    for (int k = 0; k < NNB; ++k) { a0 += w[k][m] * e0[k]; a1 += w[k][m] * e1[k]; }
    bf16x2 pk; pk[0] = (bf16_t)a0; pk[1] = (bf16_t)a1;
    *(bf16x2*)(agg_n + m * HDIM + hh) = pk;
  }
}

// ---------------------------------------------------------------------------
// GEMM1 (spatial gates): BK=64, single-buffer, compiler-scheduled, tile
// 128x64, grid 64x16 = 1024 blocks (4/CU). 8-CHUNK XOR SWIZZLE on [R][64]
// tiles (128B rows): logical 16B chunk q of row r lives at physical chunk
// q ^ (r&7). Pre-swizzled GLOBAL source + linear LDS dest (global_load_lds)
// + same XOR on read -> each 16-lane quarter covers all 8 granule slots 2x
// (conflict-free; verified pattern from round 10 at 4 chunks).
// 16 MFMA per barrier pair (2x round 10).
// ---------------------------------------------------------------------------
__global__ __launch_bounds__(256) void gemm1_kernel(
    const bf16_t* __restrict__ A, const bf16_t* __restrict__ Bt,
    const float* __restrict__ b_fg, const float* __restrict__ b_ig,
    const float* __restrict__ c_in, const float* __restrict__ h_in,
    float* __restrict__ cprime, bf16_t* __restrict__ A2)
{
  __shared__ bf16_t At[128][64];   // 16 KB
  __shared__ bf16_t Bs[64][64];    //  8 KB

  const int tid  = threadIdx.x;
  const int wave = tid >> 6, lane = tid & 63;
  const int wr = wave >> 1, wc = wave & 1;
  const int bm0 = blockIdx.x * 128;
  const int bn0 = blockIdx.y * 64;
  const int K = 2048;

  f32x4 acc[4][2] = {};

  const int srow = tid >> 3;                      // 0..31
  const int sch  = tid & 7;                       // physical 16B chunk
  const int gsw8 = (sch ^ (srow & 7)) * 8;        // pre-swizzled global chunk
  const int sch8 = sch * 8;                       // linear LDS dest
  const int frow = lane & 15;
  const int fq   = lane >> 4;                     // logical chunk within kk-half

  for (int k0 = 0; k0 < K; k0 += 64) {
#pragma unroll
    for (int r = 0; r < 4; ++r)
      load_lds16(A + (size_t)(bm0 + r * 32 + srow) * K + k0 + gsw8,
                 &At[r * 32 + srow][sch8]);
#pragma unroll
    for (int r = 0; r < 2; ++r)
      load_lds16(Bt + (size_t)(bn0 + r * 32 + srow) * K + k0 + gsw8,
                 &Bs[r * 32 + srow][sch8]);
    __syncthreads();

#pragma unroll
    for (int kk = 0; kk < 2; ++kk) {
      const int fro8 = ((kk * 4 + fq) ^ (frow & 7)) * 8;  // swizzled chunk
      bf16x8 af[4], bv[2];
#pragma unroll
      for (int i = 0; i < 4; ++i)
        af[i] = *(const bf16x8*)&At[wr * 64 + i * 16 + frow][fro8];
#pragma unroll
      for (int j = 0; j < 2; ++j)
        bv[j] = *(const bf16x8*)&Bs[wc * 32 + j * 16 + frow][fro8];
#pragma unroll
      for (int i = 0; i < 4; ++i)
#pragma unroll
        for (int j = 0; j < 2; ++j)
          acc[i][j] = __builtin_amdgcn_mfma_f32_16x16x32_bf16(af[i], bv[j], acc[i][j], 0, 0, 0);
    }
    __syncthreads();
  }

  const int col_in = lane & 15;
  const int row_in = (lane >> 4) * 4;
#pragma unroll
  for (int i = 0; i < 4; ++i) {
#pragma unroll
    for (int j = 0; j < 2; ++j) {
      const int col = bn0 + wc * 32 + j * 16 + col_in;
#pragma unroll
      for (int r = 0; r < 4; ++r) {
        const int row = bm0 + wr * 64 + i * 16 + row_in + r;
        const float v = acc[i][j][r];
        if (col < 512) {
          const float s = sigmoidf_(v + b_fg[col]);
          cprime[(size_t)row * 512 + col] = c_in[(size_t)row * 512 + col] * s;
        } else {
          const int jj = col - 512;
          const float s = sigmoidf_(v + b_ig[jj]);
          A2[(size_t)row * 640 + 128 + jj] = (bf16_t)(h_in[(size_t)row * 512 + jj] * s);
        }
      }
    }
  }
}

// ---------------------------------------------------------------------------
// GEMM2 (LSTM gates, fused finish): BK=64, tile 128x128, grid 64x16.
// Same 8-chunk XOR swizzle. Cols gate-interleaved (c = q*4+g). K=640 -> 10
// iterations, 32 MFMA per barrier pair. Fused LSTM epilogue via two-pass
// fp32 LDS exchange (epi[64][128] union, 32KB = staging size).
// ---------------------------------------------------------------------------
__global__ __launch_bounds__(256) void gemm2_kernel(
    const bf16_t* __restrict__ A, const bf16_t* __restrict__ Bt,
    const float* __restrict__ b2, const float* __restrict__ cprime,
    float* __restrict__ out)
{
  __shared__ union {
    struct { bf16_t A[128][64]; bf16_t B[128][64]; } st;  // 32 KB
    float epi[64][128];                                   // 32 KB
  } sm;

  const int tid  = threadIdx.x;
  const int wave = tid >> 6, lane = tid & 63;
  const int wr = wave >> 1, wc = wave & 1;
  const int bm0 = blockIdx.x * 128;
  const int bn0 = blockIdx.y * 128;
  const int K = 640;

  f32x4 acc[4][4] = {};

  const int srow = tid >> 3;
  const int sch  = tid & 7;
  const int gsw8 = (sch ^ (srow & 7)) * 8;
  const int sch8 = sch * 8;
  const int frow = lane & 15;
  const int fq   = lane >> 4;

  for (int k0 = 0; k0 < K; k0 += 64) {
#pragma unroll
    for (int r = 0; r < 4; ++r)
      load_lds16(A + (size_t)(bm0 + r * 32 + srow) * K + k0 + gsw8,
                 &sm.st.A[r * 32 + srow][sch8]);
#pragma unroll
    for (int r = 0; r < 4; ++r)
      load_lds16(Bt + (size_t)(bn0 + r * 32 + srow) * K + k0 + gsw8,
                 &sm.st.B[r * 32 + srow][sch8]);
    __syncthreads();

#pragma unroll
    for (int kk = 0; kk < 2; ++kk) {
      const int fro8 = ((kk * 4 + fq) ^ (frow & 7)) * 8;
      bf16x8 af[4], bv[4];
#pragma unroll
      for (int i = 0; i < 4; ++i)
        af[i] = *(const bf16x8*)&sm.st.A[wr * 64 + i * 16 + frow][fro8];
#pragma unroll
      for (int j = 0; j < 4; ++j)
        bv[j] = *(const bf16x8*)&sm.st.B[wc * 64 + j * 16 + frow][fro8];
#pragma unroll
      for (int i = 0; i < 4; ++i)
#pragma unroll
        for (int j = 0; j < 4; ++j)
          acc[i][j] = __builtin_amdgcn_mfma_f32_16x16x32_bf16(af[i], bv[j], acc[i][j], 0, 0, 0);
    }
    __syncthreads();
  }

  // Fused LSTM finish: two passes over 64-row halves through fp32 LDS.
  const int col_in = lane & 15;
  const int row_in = (lane >> 4) * 4;
  const int q0i = bn0 >> 2;           // first global q of this block (32 q's)
  const int qi  = tid & 31;           // 0..31
  const int r0  = tid >> 5;           // 0..7

#pragma unroll
  for (int p = 0; p < 2; ++p) {
    if (wr == p) {
#pragma unroll
      for (int i = 0; i < 4; ++i)
#pragma unroll
        for (int j = 0; j < 4; ++j)
#pragma unroll
          for (int r = 0; r < 4; ++r)
            sm.epi[i * 16 + row_in + r][wc * 64 + j * 16 + col_in] = acc[i][j][r];
    }
    __syncthreads();
    const float4 bb = *(const float4*)&b2[(size_t)(q0i + qi) * 4];
#pragma unroll
    for (int rr = 0; rr < 8; ++rr) {
      const int lr = r0 + rr * 8;               // 0..63 local row in this half
      const float4 g4 = *(const float4*)&sm.epi[lr][qi * 4];
      const int grow = bm0 + p * 64 + lr;
      const int q    = q0i + qi;
      const float cp = cprime[(size_t)grow * 512 + q];
      const float ig = sigmoidf_(g4.x + bb.x);
      const float fg = sigmoidf_(g4.y + bb.y);
      const float gg = tanhf(g4.z + bb.z);
      const float og = sigmoidf_(g4.w + bb.w);
      const float cn = fg * cp + ig * gg;
      const float hn = og * tanhf(cn);
      out[(size_t)grow * 512 + q] = hn;
      out[(size_t)N_ROWS * 512 + (size_t)grow * 512 + q] = cn;
    }
    __syncthreads();
  }
}

// ---------------------------------------------------------------------------
extern "C" void kernel_launch(void* const* d_in, const int* in_sizes, int n_in,
                              void* d_out, int out_size, void* d_ws, size_t ws_size,
                              hipStream_t stream) {
  const float* x     = (const float*)d_in[0];
  const float* h     = (const float*)d_in[1];
  const float* c     = (const float*)d_in[2];
  const float* hsp   = (const float*)d_in[3];
  const float* a_src = (const float*)d_in[4];
  const float* w_fg  = (const float*)d_in[5];
  const float* b_fg  = (const float*)d_in[6];
  const float* w_ig  = (const float*)d_in[7];
  const float* b_ig  = (const float*)d_in[8];
  const float* w_ih  = (const float*)d_in[9];
  const float* w_hh  = (const float*)d_in[10];
  const float* b_ih  = (const float*)d_in[11];
  const float* b_hh  = (const float*)d_in[12];
  float* out = (float*)d_out;

  uint8_t* ws = (uint8_t*)d_ws;
  bf16_t* agg    = (bf16_t*)(ws);                 // 8192*2048*2 = 33,554,432
  bf16_t* W1     = (bf16_t*)(ws + 33554432);      // 1024*2048*2 =  4,194,304
  bf16_t* W2i    = (bf16_t*)(ws + 37748736);      // 2048*640*2  =  2,621,440
  float*  b2     = (float*) (ws + 40370176);      // 2048*4      =      8,192
  bf16_t* A2     = (bf16_t*)(ws + 40378368);      // 8192*640*2  = 10,485,760
  float*  cprime = (float*) (ws + 50864128);      // 8192*512*4  = 16,777,216
  // total 67,641,344 bytes

  pack_kernel<<<4360, 256, 0, stream>>>(w_fg, w_ig, w_ih, w_hh, b_ih, b_hh, x,
                                        W1, W2i, b2, A2);
  attn_agg_kernel<<<N_ROWS, 256, 0, stream>>>(h, hsp, a_src, agg);
  gemm1_kernel<<<dim3(64, 16), 256, 0, stream>>>(
      agg, W1, b_fg, b_ig, c, h, cprime, A2);
  gemm2_kernel<<<dim3(64, 16), 256, 0, stream>>>(
      A2, W2i, b2, cprime, out);
}